// Round 1
// baseline (2682.858 us; speedup 1.0000x reference)
//
#include <hip/hip_runtime.h>
#include <stdint.h>

typedef unsigned long long u64;
typedef uint32_t u32;

#define NBOX 8192
#define THRF 0.3f
#define EPSF 1e-6f

// ---------- ws layout (bytes) ----------
// keys    : [0,       65536)   u64[8192]
// order   : [65536,   98304)   int[8192]
// soa     : [98304,  360448)   8 arrays of float[8192]: x1,x2,z1,z2,area,ymin,ymax,h
// sboxes  : [360448, 589824)   float[8192*7] sorted boxes
// keepw   : [589824, 590848)   u64[128] keep bits
// mask    : [1048576, 9437184) u64[8192*128] suppression bitmask (upper-tri words only)

#define WS_KEYS   0
#define WS_ORDER  65536
#define WS_SOA    98304
#define WS_SBOX   360448
#define WS_KEEPW  589824
#define WS_MASK   1048576

struct DBox { float x1, x2, z1, z2, area, ymin, ymax, h; };

__device__ __forceinline__ DBox derive_box(const float v[7]) {
    float cx = v[0], cy = v[1], cz = v[2];
    float dx = __fmul_rn(v[3], 0.5f);
    float dz = __fmul_rn(v[4], 0.5f);
    float h = v[5], yaw = v[6];
    float c = cosf(yaw), sn = sinf(yaw);
    // corners gx = (lx*c - lz*s) + cx, lx=±dx, lz=±dz
    float A = __fmul_rn(dx, c), B = __fmul_rn(dz, sn);
    float P = __fmul_rn(dx, sn), Q = __fmul_rn(dz, c);
    float mX = fmaxf(fabsf(__fadd_rn(A, B)), fabsf(__fsub_rn(A, B)));
    float mZ = fmaxf(fabsf(__fadd_rn(P, Q)), fabsf(__fsub_rn(P, Q)));
    DBox d;
    d.x1 = __fsub_rn(cx, mX); d.x2 = __fadd_rn(cx, mX);
    d.z1 = __fsub_rn(cz, mZ); d.z2 = __fadd_rn(cz, mZ);
    d.area = __fmul_rn(__fsub_rn(d.x2, d.x1), __fsub_rn(d.z2, d.z1));
    float hh = __fmul_rn(h, 0.5f);
    d.ymin = __fsub_rn(cy, hh); d.ymax = __fadd_rn(cy, hh);
    d.h = h;
    return d;
}

__device__ __forceinline__ float iou_pair(const DBox& a, const DBox& b) {
    float yov = fmaxf(__fsub_rn(fminf(a.ymax, b.ymax), fmaxf(a.ymin, b.ymin)), 0.0f);
    float hun = __fsub_rn(__fadd_rn(a.h, b.h), yov);
    float hr  = __fdiv_rn(yov, __fadd_rn(hun, EPSF));
    float xw  = fmaxf(__fsub_rn(fminf(a.x2, b.x2), fmaxf(a.x1, b.x1)), 0.0f);
    float zw  = fmaxf(__fsub_rn(fminf(a.z2, b.z2), fmaxf(a.z1, b.z1)), 0.0f);
    float inter = __fmul_rn(xw, zw);
    float uni = __fsub_rn(__fadd_rn(a.area, b.area), inter);
    return __fmul_rn(__fdiv_rn(inter, __fadd_rn(uni, EPSF)), hr);
}

__device__ __forceinline__ u64 readlane64(u64 v, int lane) {
    u32 lo = (u32)__builtin_amdgcn_readlane((int)(u32)(v & 0xffffffffull), lane);
    u32 hi = (u32)__builtin_amdgcn_readlane((int)(u32)(v >> 32), lane);
    return ((u64)hi << 32) | (u64)lo;
}

// K1: composite sort key: descending score, ties by ascending original index
__global__ __launch_bounds__(256) void key_kernel(const float* __restrict__ s0,
                                                  const float* __restrict__ s1,
                                                  u64* __restrict__ keys, int N) {
    int i = blockIdx.x * 256 + threadIdx.x;
    float sc = (i < N) ? s0[i] : s1[i - N];
    u32 b = __float_as_uint(sc);       // scores >= 0: bit order == value order
    keys[i] = ((u64)(~b) << 13) | (u32)i;
}

// K2: rank by counting smaller keys (keys unique), scatter order[rank]=i
__global__ __launch_bounds__(256) void rank_kernel(const u64* __restrict__ keys,
                                                   int* __restrict__ order) {
    __shared__ u64 lk[NBOX];           // 64 KiB
    for (int j = threadIdx.x; j < NBOX; j += 256) lk[j] = keys[j];
    __syncthreads();
    int e = blockIdx.x * 256 + threadIdx.x;
    u64 k = lk[e];
    int rank = 0;
    const ulonglong2* p2 = (const ulonglong2*)lk;
    #pragma unroll 8
    for (int j = 0; j < NBOX / 2; ++j) {
        ulonglong2 v = p2[j];
        rank += (v.x < k);
        rank += (v.y < k);
    }
    order[rank] = e;
}

// K3: gather sorted boxes, precompute per-box derived quantities (SoA)
__global__ __launch_bounds__(256) void prep_kernel(const float* __restrict__ boxes0,
                                                   const float* __restrict__ boxes1,
                                                   const int* __restrict__ order,
                                                   float* __restrict__ soa,
                                                   float* __restrict__ sboxes, int N) {
    int s = blockIdx.x * 256 + threadIdx.x;
    int o = order[s];
    const float* bp = (o < N) ? boxes0 + (size_t)o * 7 : boxes1 + (size_t)(o - N) * 7;
    float v[7];
    #pragma unroll
    for (int c = 0; c < 7; ++c) { v[c] = bp[c]; sboxes[(size_t)s * 7 + c] = v[c]; }
    DBox d = derive_box(v);
    soa[0 * NBOX + s] = d.x1;  soa[1 * NBOX + s] = d.x2;
    soa[2 * NBOX + s] = d.z1;  soa[3 * NBOX + s] = d.z2;
    soa[4 * NBOX + s] = d.area; soa[5 * NBOX + s] = d.ymin;
    soa[6 * NBOX + s] = d.ymax; soa[7 * NBOX + s] = d.h;
}

// K4: suppression bitmask, upper triangle. Block b owns rows {b + 256k}, k<32.
// For row r, writes all words w >= 4*(r>>8) (zeros where col<=r).
__global__ __launch_bounds__(256) void mask_kernel(const float* __restrict__ soa,
                                                   u64* __restrict__ mask) {
    __shared__ float col[8][256];
    __shared__ float rowd[8][32];
    int b = blockIdx.x;            // 0..255
    int tid = threadIdx.x;
    for (int i = tid; i < 8 * 32; i += 256) {
        int arr = i >> 5, k = i & 31;
        rowd[arr][k] = soa[arr * NBOX + (b + 256 * k)];
    }
    int wv = tid >> 6, lane = tid & 63;
    for (int t = 0; t < 32; ++t) {
        __syncthreads();
        for (int i = tid; i < 8 * 256; i += 256) {
            int arr = i >> 8, j = i & 255;
            col[arr][j] = soa[arr * NBOX + t * 256 + j];
        }
        __syncthreads();
        int kmax = (256 * t + 255 - b) >> 8;   // rows active in this col tile
        if (kmax > 31) kmax = 31;
        for (int k = wv; k <= kmax; k += 4) {
            int r = b + 256 * k;
            DBox rb;
            rb.x1 = rowd[0][k]; rb.x2 = rowd[1][k]; rb.z1 = rowd[2][k]; rb.z2 = rowd[3][k];
            rb.area = rowd[4][k]; rb.ymin = rowd[5][k]; rb.ymax = rowd[6][k]; rb.h = rowd[7][k];
            #pragma unroll
            for (int sub = 0; sub < 4; ++sub) {
                int j = sub * 64 + lane;
                int cidx = t * 256 + j;
                DBox cb;
                cb.x1 = col[0][j]; cb.x2 = col[1][j]; cb.z1 = col[2][j]; cb.z2 = col[3][j];
                cb.area = col[4][j]; cb.ymin = col[5][j]; cb.ymax = col[6][j]; cb.h = col[7][j];
                float iou = iou_pair(rb, cb);
                bool pred = (cidx > r) && (iou >= THRF);
                u64 word = __ballot(pred);
                if (lane == 0) mask[(size_t)r * 128 + (t * 4 + sub)] = word;
            }
        }
    }
}

// K5: sequential greedy NMS over the bitmask. Single wave.
// remv word `lane` in r0, word `lane+64` in r1.
__global__ __launch_bounds__(64) void nms_kernel(const u64* __restrict__ mask,
                                                 u64* __restrict__ keepw) {
    int lane = threadIdx.x;
    u64 r0 = 0, r1 = 0;
    for (int w = 0; w < 128; ++w) {
        int src = w & 63;
        u64 sel = (w < 64) ? r0 : r1;
        u64 S = readlane64(sel, src);              // current remv word w (uniform)
        // diagonal 64x64 block: lane l holds word w of row 64w+l
        u64 dw = mask[(size_t)(w * 64 + lane) * 128 + w];
        u64 keptm = 0, covered = S;
        int p = 0;
        while (p < 64) {
            u64 cand = ~covered & ((~0ull) << p);  // first undecided, unsuppressed row
            if (!cand) break;
            int u = (int)__builtin_ctzll(cand);
            keptm |= (1ull << u);
            covered |= readlane64(dw, u);          // in-chunk suppression
            p = u + 1;
        }
        if (lane == 0) keepw[w] = keptm;
        // apply kept rows' full masks to remv (valid words >= vstart only)
        int vstart = w & ~3;
        const u64* rp = mask + (size_t)w * 64 * 128;
        u64 m = keptm;
        while (m) {
            int u = (int)__builtin_ctzll(m);
            m &= m - 1;
            const u64* rr = rp + (size_t)u * 128;
            if (lane >= vstart)        r0 |= rr[lane];
            if (lane + 64 >= vstart)   r1 |= rr[lane + 64];
        }
    }
}

// K6: pair fusion + masking, writes fused (8192x7) then keep (8192) to d_out
__global__ __launch_bounds__(256) void fuse_kernel(const float* __restrict__ boxes1,
                                                   const int* __restrict__ order,
                                                   const float* __restrict__ soa,
                                                   const float* __restrict__ sboxes,
                                                   const u64* __restrict__ keepw,
                                                   float* __restrict__ out, int N) {
    int s = blockIdx.x * 256 + threadIdx.x;
    bool keep = (keepw[s >> 6] >> (s & 63)) & 1ull;
    float res[7];
    if (!keep) {
        #pragma unroll
        for (int c = 0; c < 7; ++c) res[c] = 0.0f;
    } else {
        int o = order[s];
        float a[7];
        #pragma unroll
        for (int c = 0; c < 7; ++c) a[c] = sboxes[(size_t)s * 7 + c];
        if (o >= N) {
            #pragma unroll
            for (int c = 0; c < 7; ++c) res[c] = a[c];
        } else {
            float bv[7];
            #pragma unroll
            for (int c = 0; c < 7; ++c) bv[c] = boxes1[(size_t)o * 7 + c];
            DBox da;
            da.x1 = soa[0 * NBOX + s]; da.x2 = soa[1 * NBOX + s];
            da.z1 = soa[2 * NBOX + s]; da.z2 = soa[3 * NBOX + s];
            da.area = soa[4 * NBOX + s]; da.ymin = soa[5 * NBOX + s];
            da.ymax = soa[6 * NBOX + s]; da.h = soa[7 * NBOX + s];
            DBox db = derive_box(bv);
            float iaa = iou_pair(da, da);
            float iab = iou_pair(da, db);
            float ibb = iou_pair(db, db);
            float im0 = fmaxf(iaa, iab);
            float im1 = fmaxf(iab, ibb);
            bool m0 = im0 > THRF, m1 = im1 > THRF;
            float w0 = m0 ? im0 : 0.0f;
            float w1 = m1 ? im1 : 0.0f;
            float den = __fadd_rn(w0, w1);
            float den_safe = (den == 0.0f) ? 1.0f : den;
            bool any = m0 || m1;
            #pragma unroll
            for (int c = 0; c < 7; ++c) {
                float fw = __fdiv_rn(__fadd_rn(__fmul_rn(a[c], w0), __fmul_rn(bv[c], w1)), den_safe);
                float fm = __fmul_rn(__fadd_rn(a[c], bv[c]), 0.5f);
                res[c] = any ? fw : fm;
            }
        }
    }
    #pragma unroll
    for (int c = 0; c < 7; ++c) out[(size_t)s * 7 + c] = res[c];
    out[(size_t)NBOX * 7 + s] = keep ? 1.0f : 0.0f;
}

extern "C" void kernel_launch(void* const* d_in, const int* in_sizes, int n_in,
                              void* d_out, int out_size, void* d_ws, size_t ws_size,
                              hipStream_t stream) {
    (void)n_in; (void)out_size; (void)ws_size;
    const float* boxes0  = (const float*)d_in[0];
    const float* boxes1  = (const float*)d_in[1];
    const float* scores0 = (const float*)d_in[2];
    const float* scores1 = (const float*)d_in[3];
    int N = in_sizes[2];   // 4096

    char* ws = (char*)d_ws;
    u64*   keys   = (u64*)(ws + WS_KEYS);
    int*   order  = (int*)(ws + WS_ORDER);
    float* soa    = (float*)(ws + WS_SOA);
    float* sboxes = (float*)(ws + WS_SBOX);
    u64*   keepw  = (u64*)(ws + WS_KEEPW);
    u64*   mask   = (u64*)(ws + WS_MASK);
    float* out    = (float*)d_out;

    key_kernel <<<NBOX / 256, 256, 0, stream>>>(scores0, scores1, keys, N);
    rank_kernel<<<NBOX / 256, 256, 0, stream>>>(keys, order);
    prep_kernel<<<NBOX / 256, 256, 0, stream>>>(boxes0, boxes1, order, soa, sboxes, N);
    mask_kernel<<<256, 256, 0, stream>>>(soa, mask);
    nms_kernel <<<1, 64, 0, stream>>>(mask, keepw);
    fuse_kernel<<<NBOX / 256, 256, 0, stream>>>(boxes1, order, soa, sboxes, keepw, out, N);
}

// Round 2
// 1132.402 us; speedup vs baseline: 2.3692x; 2.3692x over previous
//
#include <hip/hip_runtime.h>
#include <stdint.h>

typedef unsigned long long u64;
typedef uint32_t u32;

#define NBOX 8192
#define THRF 0.3f
#define EPSF 1e-6f

// ---------- ws layout (bytes) ----------
// keys    : [0,       65536)   u64[8192]
// order   : [65536,   98304)   int[8192]
// soa     : [98304,  360448)   8 arrays of float[8192]: x1,x2,z1,z2,area,ymin,ymax,h
// sboxes  : [360448, 589824)   float[8192*7] sorted boxes
// keepw   : [589824, 590848)   u64[128] keep bits
// mask    : [1048576, 9437184) u64[8192*128] suppression bitmask (upper-tri words only)

#define WS_KEYS   0
#define WS_ORDER  65536
#define WS_SOA    98304
#define WS_SBOX   360448
#define WS_KEEPW  589824
#define WS_MASK   1048576

struct DBox { float x1, x2, z1, z2, area, ymin, ymax, h; };

__device__ __forceinline__ DBox derive_box(const float v[7]) {
    float cx = v[0], cy = v[1], cz = v[2];
    float dx = __fmul_rn(v[3], 0.5f);
    float dz = __fmul_rn(v[4], 0.5f);
    float h = v[5], yaw = v[6];
    float c = cosf(yaw), sn = sinf(yaw);
    float A = __fmul_rn(dx, c), B = __fmul_rn(dz, sn);
    float P = __fmul_rn(dx, sn), Q = __fmul_rn(dz, c);
    float mX = fmaxf(fabsf(__fadd_rn(A, B)), fabsf(__fsub_rn(A, B)));
    float mZ = fmaxf(fabsf(__fadd_rn(P, Q)), fabsf(__fsub_rn(P, Q)));
    DBox d;
    d.x1 = __fsub_rn(cx, mX); d.x2 = __fadd_rn(cx, mX);
    d.z1 = __fsub_rn(cz, mZ); d.z2 = __fadd_rn(cz, mZ);
    d.area = __fmul_rn(__fsub_rn(d.x2, d.x1), __fsub_rn(d.z2, d.z1));
    float hh = __fmul_rn(h, 0.5f);
    d.ymin = __fsub_rn(cy, hh); d.ymax = __fadd_rn(cy, hh);
    d.h = h;
    return d;
}

__device__ __forceinline__ float iou_pair(const DBox& a, const DBox& b) {
    float yov = fmaxf(__fsub_rn(fminf(a.ymax, b.ymax), fmaxf(a.ymin, b.ymin)), 0.0f);
    float hun = __fsub_rn(__fadd_rn(a.h, b.h), yov);
    float hr  = __fdiv_rn(yov, __fadd_rn(hun, EPSF));
    float xw  = fmaxf(__fsub_rn(fminf(a.x2, b.x2), fmaxf(a.x1, b.x1)), 0.0f);
    float zw  = fmaxf(__fsub_rn(fminf(a.z2, b.z2), fmaxf(a.z1, b.z1)), 0.0f);
    float inter = __fmul_rn(xw, zw);
    float uni = __fsub_rn(__fadd_rn(a.area, b.area), inter);
    return __fmul_rn(__fdiv_rn(inter, __fadd_rn(uni, EPSF)), hr);
}

__device__ __forceinline__ u64 readlane64(u64 v, int lane) {
    u32 lo = (u32)__builtin_amdgcn_readlane((int)(u32)(v & 0xffffffffull), lane);
    u32 hi = (u32)__builtin_amdgcn_readlane((int)(u32)(v >> 32), lane);
    return ((u64)hi << 32) | (u64)lo;
}

// K1: composite sort key: descending score, ties by ascending original index
__global__ __launch_bounds__(256) void key_kernel(const float* __restrict__ s0,
                                                  const float* __restrict__ s1,
                                                  u64* __restrict__ keys, int N) {
    int i = blockIdx.x * 256 + threadIdx.x;
    float sc = (i < N) ? s0[i] : s1[i - N];
    u32 b = __float_as_uint(sc);       // scores >= 0: bit order == value order
    keys[i] = ((u64)(~b) << 13) | (u32)i;
}

// K2: rank by counting smaller keys (keys unique), scatter order[rank]=i
__global__ __launch_bounds__(256) void rank_kernel(const u64* __restrict__ keys,
                                                   int* __restrict__ order) {
    __shared__ u64 lk[NBOX];           // 64 KiB
    for (int j = threadIdx.x; j < NBOX; j += 256) lk[j] = keys[j];
    __syncthreads();
    int e = blockIdx.x * 256 + threadIdx.x;
    u64 k = lk[e];
    int rank = 0;
    const ulonglong2* p2 = (const ulonglong2*)lk;
    #pragma unroll 8
    for (int j = 0; j < NBOX / 2; ++j) {
        ulonglong2 v = p2[j];
        rank += (v.x < k);
        rank += (v.y < k);
    }
    order[rank] = e;
}

// K3: gather sorted boxes, precompute per-box derived quantities (SoA)
__global__ __launch_bounds__(256) void prep_kernel(const float* __restrict__ boxes0,
                                                   const float* __restrict__ boxes1,
                                                   const int* __restrict__ order,
                                                   float* __restrict__ soa,
                                                   float* __restrict__ sboxes, int N) {
    int s = blockIdx.x * 256 + threadIdx.x;
    int o = order[s];
    const float* bp = (o < N) ? boxes0 + (size_t)o * 7 : boxes1 + (size_t)(o - N) * 7;
    float v[7];
    #pragma unroll
    for (int c = 0; c < 7; ++c) { v[c] = bp[c]; sboxes[(size_t)s * 7 + c] = v[c]; }
    DBox d = derive_box(v);
    soa[0 * NBOX + s] = d.x1;  soa[1 * NBOX + s] = d.x2;
    soa[2 * NBOX + s] = d.z1;  soa[3 * NBOX + s] = d.z2;
    soa[4 * NBOX + s] = d.area; soa[5 * NBOX + s] = d.ymin;
    soa[6 * NBOX + s] = d.ymax; soa[7 * NBOX + s] = d.h;
}

// K4: suppression bitmask, upper triangle. Block b owns rows {b + 256k}, k<32.
__global__ __launch_bounds__(256) void mask_kernel(const float* __restrict__ soa,
                                                   u64* __restrict__ mask) {
    __shared__ float col[8][256];
    __shared__ float rowd[8][32];
    int b = blockIdx.x;            // 0..255
    int tid = threadIdx.x;
    for (int i = tid; i < 8 * 32; i += 256) {
        int arr = i >> 5, k = i & 31;
        rowd[arr][k] = soa[arr * NBOX + (b + 256 * k)];
    }
    int wv = tid >> 6, lane = tid & 63;
    for (int t = 0; t < 32; ++t) {
        __syncthreads();
        for (int i = tid; i < 8 * 256; i += 256) {
            int arr = i >> 8, j = i & 255;
            col[arr][j] = soa[arr * NBOX + t * 256 + j];
        }
        __syncthreads();
        int kmax = (256 * t + 255 - b) >> 8;   // rows active in this col tile
        if (kmax > 31) kmax = 31;
        for (int k = wv; k <= kmax; k += 4) {
            int r = b + 256 * k;
            DBox rb;
            rb.x1 = rowd[0][k]; rb.x2 = rowd[1][k]; rb.z1 = rowd[2][k]; rb.z2 = rowd[3][k];
            rb.area = rowd[4][k]; rb.ymin = rowd[5][k]; rb.ymax = rowd[6][k]; rb.h = rowd[7][k];
            #pragma unroll
            for (int sub = 0; sub < 4; ++sub) {
                int j = sub * 64 + lane;
                int cidx = t * 256 + j;
                DBox cb;
                cb.x1 = col[0][j]; cb.x2 = col[1][j]; cb.z1 = col[2][j]; cb.z2 = col[3][j];
                cb.area = col[4][j]; cb.ymin = col[5][j]; cb.ymax = col[6][j]; cb.h = col[7][j];
                float iou = iou_pair(rb, cb);
                bool pred = (cidx > r) && (iou >= THRF);
                u64 word = __ballot(pred);
                if (lane == 0) mask[(size_t)r * 128 + (t * 4 + sub)] = word;
            }
        }
    }
}

// K5: sequential greedy NMS, 1 block x 1024 threads (16 waves).
// Thread t owns remv word (t&127), replica (t>>7). Per word-iteration:
//  (1) the 8 replica owners of word w publish acc -> LDS, barrier
//  (2) wave 0 OR-reduces them, runs the serial in-chunk decide using the
//      register-prefetched diagonal 64x64 block, publishes keptm, barrier
//  (3) all 1024 threads apply the kept rows' masks: replica r takes every
//      8th kept row, one coalesced 8B load per (row, word>w) pair.
__global__ __launch_bounds__(1024) void nms_kernel(const u64* __restrict__ mask,
                                                   u64* __restrict__ keepw) {
    __shared__ u64 redsh[8];
    __shared__ u64 keptm_sh;
    int t = threadIdx.x;
    int lane = t & 63;
    int wid = t >> 6;
    int myword = t & 127;
    int slot = t >> 7;
    u64 acc = 0;

    u64 dw_pref = 0;
    if (wid == 0) dw_pref = mask[(size_t)lane * 128 + 0];   // diag block for w=0

    for (int w = 0; w < 128; ++w) {
        if (myword == w) redsh[slot] = acc;
        __syncthreads();
        if (wid == 0) {
            u64 S = redsh[0] | redsh[1] | redsh[2] | redsh[3]
                  | redsh[4] | redsh[5] | redsh[6] | redsh[7];
            u64 dw = dw_pref;
            if (w + 1 < 128)   // prefetch next diagonal block
                dw_pref = mask[(size_t)((w + 1) * 64 + lane) * 128 + (w + 1)];
            u64 keptm = 0, covered = S;
            int p = 0;
            while (p < 64) {
                u64 cand = ~covered & ((~0ull) << p);
                if (!cand) break;
                int u = (int)__builtin_ctzll(cand);
                keptm |= (1ull << u);
                covered |= readlane64(dw, u);
                p = u + 1;
            }
            if (lane == 0) { keptm_sh = keptm; keepw[w] = keptm; }
        }
        __syncthreads();
        u64 km = keptm_sh;
        if (myword > w) {
            const u64* rp = mask + (size_t)w * 64 * 128 + myword;
            u64 m = km;
            int c = 0;
            while (m) {
                int u = (int)__builtin_ctzll(m);
                m &= m - 1;
                if ((c & 7) == slot) acc |= rp[(size_t)u * 128];
                ++c;
            }
        }
    }
}

// K6: pair fusion + masking, writes fused (8192x7) then keep (8192) to d_out
__global__ __launch_bounds__(256) void fuse_kernel(const float* __restrict__ boxes1,
                                                   const int* __restrict__ order,
                                                   const float* __restrict__ soa,
                                                   const float* __restrict__ sboxes,
                                                   const u64* __restrict__ keepw,
                                                   float* __restrict__ out, int N) {
    int s = blockIdx.x * 256 + threadIdx.x;
    bool keep = (keepw[s >> 6] >> (s & 63)) & 1ull;
    float res[7];
    if (!keep) {
        #pragma unroll
        for (int c = 0; c < 7; ++c) res[c] = 0.0f;
    } else {
        int o = order[s];
        float a[7];
        #pragma unroll
        for (int c = 0; c < 7; ++c) a[c] = sboxes[(size_t)s * 7 + c];
        if (o >= N) {
            #pragma unroll
            for (int c = 0; c < 7; ++c) res[c] = a[c];
        } else {
            float bv[7];
            #pragma unroll
            for (int c = 0; c < 7; ++c) bv[c] = boxes1[(size_t)o * 7 + c];
            DBox da;
            da.x1 = soa[0 * NBOX + s]; da.x2 = soa[1 * NBOX + s];
            da.z1 = soa[2 * NBOX + s]; da.z2 = soa[3 * NBOX + s];
            da.area = soa[4 * NBOX + s]; da.ymin = soa[5 * NBOX + s];
            da.ymax = soa[6 * NBOX + s]; da.h = soa[7 * NBOX + s];
            DBox db = derive_box(bv);
            float iaa = iou_pair(da, da);
            float iab = iou_pair(da, db);
            float ibb = iou_pair(db, db);
            float im0 = fmaxf(iaa, iab);
            float im1 = fmaxf(iab, ibb);
            bool m0 = im0 > THRF, m1 = im1 > THRF;
            float w0 = m0 ? im0 : 0.0f;
            float w1 = m1 ? im1 : 0.0f;
            float den = __fadd_rn(w0, w1);
            float den_safe = (den == 0.0f) ? 1.0f : den;
            bool any = m0 || m1;
            #pragma unroll
            for (int c = 0; c < 7; ++c) {
                float fw = __fdiv_rn(__fadd_rn(__fmul_rn(a[c], w0), __fmul_rn(bv[c], w1)), den_safe);
                float fm = __fmul_rn(__fadd_rn(a[c], bv[c]), 0.5f);
                res[c] = any ? fw : fm;
            }
        }
    }
    #pragma unroll
    for (int c = 0; c < 7; ++c) out[(size_t)s * 7 + c] = res[c];
    out[(size_t)NBOX * 7 + s] = keep ? 1.0f : 0.0f;
}

extern "C" void kernel_launch(void* const* d_in, const int* in_sizes, int n_in,
                              void* d_out, int out_size, void* d_ws, size_t ws_size,
                              hipStream_t stream) {
    (void)n_in; (void)out_size; (void)ws_size;
    const float* boxes0  = (const float*)d_in[0];
    const float* boxes1  = (const float*)d_in[1];
    const float* scores0 = (const float*)d_in[2];
    const float* scores1 = (const float*)d_in[3];
    int N = in_sizes[2];   // 4096

    char* ws = (char*)d_ws;
    u64*   keys   = (u64*)(ws + WS_KEYS);
    int*   order  = (int*)(ws + WS_ORDER);
    float* soa    = (float*)(ws + WS_SOA);
    float* sboxes = (float*)(ws + WS_SBOX);
    u64*   keepw  = (u64*)(ws + WS_KEEPW);
    u64*   mask   = (u64*)(ws + WS_MASK);
    float* out    = (float*)d_out;

    key_kernel <<<NBOX / 256, 256, 0, stream>>>(scores0, scores1, keys, N);
    rank_kernel<<<NBOX / 256, 256, 0, stream>>>(keys, order);
    prep_kernel<<<NBOX / 256, 256, 0, stream>>>(boxes0, boxes1, order, soa, sboxes, N);
    mask_kernel<<<256, 256, 0, stream>>>(soa, mask);
    nms_kernel <<<1, 1024, 0, stream>>>(mask, keepw);
    fuse_kernel<<<NBOX / 256, 256, 0, stream>>>(boxes1, order, soa, sboxes, keepw, out, N);
}

// Round 3
// 874.439 us; speedup vs baseline: 3.0681x; 1.2950x over previous
//
#include <hip/hip_runtime.h>
#include <stdint.h>

typedef unsigned long long u64;
typedef uint32_t u32;

#define NBOX 8192
#define THRF 0.3f
#define EPSF 1e-6f

// ---------- ws layout (bytes) ----------
// order   : [65536,   98304)   int[8192]
// soa     : [98304,  360448)   8 arrays of float[8192]: x1,x2,z1,z2,area,ymin,ymax,h
// sboxes  : [360448, 589824)   float[8192*7] sorted boxes
// keepw   : [589824, 590848)   u64[128] keep bits
// mask    : [1048576, 9437184) u64[8192*128] suppression bitmask (upper-tri words only)

#define WS_ORDER  65536
#define WS_SOA    98304
#define WS_SBOX   360448
#define WS_KEEPW  589824
#define WS_MASK   1048576

struct DBox { float x1, x2, z1, z2, area, ymin, ymax, h; };

__device__ __forceinline__ DBox derive_box(const float v[7]) {
    float cx = v[0], cy = v[1], cz = v[2];
    float dx = __fmul_rn(v[3], 0.5f);
    float dz = __fmul_rn(v[4], 0.5f);
    float h = v[5], yaw = v[6];
    float c = cosf(yaw), sn = sinf(yaw);
    float A = __fmul_rn(dx, c), B = __fmul_rn(dz, sn);
    float P = __fmul_rn(dx, sn), Q = __fmul_rn(dz, c);
    float mX = fmaxf(fabsf(__fadd_rn(A, B)), fabsf(__fsub_rn(A, B)));
    float mZ = fmaxf(fabsf(__fadd_rn(P, Q)), fabsf(__fsub_rn(P, Q)));
    DBox d;
    d.x1 = __fsub_rn(cx, mX); d.x2 = __fadd_rn(cx, mX);
    d.z1 = __fsub_rn(cz, mZ); d.z2 = __fadd_rn(cz, mZ);
    d.area = __fmul_rn(__fsub_rn(d.x2, d.x1), __fsub_rn(d.z2, d.z1));
    float hh = __fmul_rn(h, 0.5f);
    d.ymin = __fsub_rn(cy, hh); d.ymax = __fadd_rn(cy, hh);
    d.h = h;
    return d;
}

__device__ __forceinline__ float iou_pair(const DBox& a, const DBox& b) {
    float yov = fmaxf(__fsub_rn(fminf(a.ymax, b.ymax), fmaxf(a.ymin, b.ymin)), 0.0f);
    float hun = __fsub_rn(__fadd_rn(a.h, b.h), yov);
    float hr  = __fdiv_rn(yov, __fadd_rn(hun, EPSF));
    float xw  = fmaxf(__fsub_rn(fminf(a.x2, b.x2), fmaxf(a.x1, b.x1)), 0.0f);
    float zw  = fmaxf(__fsub_rn(fminf(a.z2, b.z2), fmaxf(a.z1, b.z1)), 0.0f);
    float inter = __fmul_rn(xw, zw);
    float uni = __fsub_rn(__fadd_rn(a.area, b.area), inter);
    return __fmul_rn(__fdiv_rn(inter, __fadd_rn(uni, EPSF)), hr);
}

__device__ __forceinline__ u64 readlane64(u64 v, int lane) {
    u32 lo = (u32)__builtin_amdgcn_readlane((int)(u32)(v & 0xffffffffull), lane);
    u32 hi = (u32)__builtin_amdgcn_readlane((int)(u32)(v >> 32), lane);
    return ((u64)hi << 32) | (u64)lo;
}

__device__ __forceinline__ u64 wave_or64(u64 v) {
    #pragma unroll
    for (int m = 1; m < 64; m <<= 1) {
        u32 lo = (u32)v, hi = (u32)(v >> 32);
        lo |= (u32)__shfl_xor((int)lo, m, 64);
        hi |= (u32)__shfl_xor((int)hi, m, 64);
        v = ((u64)hi << 32) | (u64)lo;
    }
    return v;
}

// K1: fused key-build + O(n^2) rank + gather/derive. 128 blocks x 1 wave.
// One wave per block avoids intra-CU LDS serialization on the broadcast scan.
__global__ __launch_bounds__(64) void sortprep_kernel(const float* __restrict__ s0,
                                                      const float* __restrict__ s1,
                                                      const float* __restrict__ boxes0,
                                                      const float* __restrict__ boxes1,
                                                      int* __restrict__ order,
                                                      float* __restrict__ soa,
                                                      float* __restrict__ sboxes, int N) {
    __shared__ u64 lk[NBOX];           // 64 KiB
    int tid = threadIdx.x;
    for (int j = tid; j < NBOX; j += 64) {
        float sc = (j < N) ? s0[j] : s1[j - N];
        lk[j] = ((u64)(~__float_as_uint(sc)) << 13) | (u32)j;   // scores>=0: bits order==value order
    }
    __syncthreads();
    int e = blockIdx.x * 64 + tid;
    u64 k = lk[e];
    int rank = 0;
    const ulonglong2* p2 = (const ulonglong2*)lk;
    #pragma unroll 8
    for (int j = 0; j < NBOX / 2; ++j) {
        ulonglong2 v = p2[j];
        rank += (v.x < k);
        rank += (v.y < k);
    }
    order[rank] = e;
    const float* bp = (e < N) ? boxes0 + (size_t)e * 7 : boxes1 + (size_t)(e - N) * 7;
    float v[7];
    #pragma unroll
    for (int c = 0; c < 7; ++c) { v[c] = bp[c]; sboxes[(size_t)rank * 7 + c] = v[c]; }
    DBox d = derive_box(v);
    soa[0 * NBOX + rank] = d.x1;  soa[1 * NBOX + rank] = d.x2;
    soa[2 * NBOX + rank] = d.z1;  soa[3 * NBOX + rank] = d.z2;
    soa[4 * NBOX + rank] = d.area; soa[5 * NBOX + rank] = d.ymin;
    soa[6 * NBOX + rank] = d.ymax; soa[7 * NBOX + rank] = d.h;
}

// K2: suppression bitmask, upper triangle. Block b owns rows {b + 256k}, k<32.
// For row r, writes all words w >= 4*(r>>8) (zeros where col<=r).
__global__ __launch_bounds__(256) void mask_kernel(const float* __restrict__ soa,
                                                   u64* __restrict__ mask) {
    __shared__ float col[8][256];
    __shared__ float rowd[8][32];
    int b = blockIdx.x;            // 0..255
    int tid = threadIdx.x;
    for (int i = tid; i < 8 * 32; i += 256) {
        int arr = i >> 5, k = i & 31;
        rowd[arr][k] = soa[arr * NBOX + (b + 256 * k)];
    }
    int wv = tid >> 6, lane = tid & 63;
    for (int t = 0; t < 32; ++t) {
        __syncthreads();
        for (int i = tid; i < 8 * 256; i += 256) {
            int arr = i >> 8, j = i & 255;
            col[arr][j] = soa[arr * NBOX + t * 256 + j];
        }
        __syncthreads();
        int kmax = (256 * t + 255 - b) >> 8;   // rows active in this col tile
        if (kmax > 31) kmax = 31;
        for (int k = wv; k <= kmax; k += 4) {
            int r = b + 256 * k;
            DBox rb;
            rb.x1 = rowd[0][k]; rb.x2 = rowd[1][k]; rb.z1 = rowd[2][k]; rb.z2 = rowd[3][k];
            rb.area = rowd[4][k]; rb.ymin = rowd[5][k]; rb.ymax = rowd[6][k]; rb.h = rowd[7][k];
            #pragma unroll
            for (int sub = 0; sub < 4; ++sub) {
                int j = sub * 64 + lane;
                int cidx = t * 256 + j;
                DBox cb;
                cb.x1 = col[0][j]; cb.x2 = col[1][j]; cb.z1 = col[2][j]; cb.z2 = col[3][j];
                cb.area = col[4][j]; cb.ymin = col[5][j]; cb.ymax = col[6][j]; cb.h = col[7][j];
                float iou = iou_pair(rb, cb);
                bool pred = (cidx > r) && (iou >= THRF);
                u64 word = __ballot(pred);
                if (lane == 0) mask[(size_t)r * 128 + (t * 4 + sub)] = word;
            }
        }
    }
}

// K3: greedy NMS, 1 block x 1024 threads, wave-specialized pipeline.
// Wave 0: decider. Per iter w: decide chunk w from (Sreg, prefetched diag w),
//   publish kept-list, barrier, then S_{w+1} = OR(applier pubs: chunks<=w-1)
//   | wave_or(sel(prefetched col w+1 of chunk w, keptm_w)).
//   Diag/col prefetches for iter w+1 are issued BEFORE the decide of iter w.
// Waves 2..15: appliers, 128 words x 7 replicas. At iter w they OR the
//   kept rows of chunk w-1 (from the LDS kept-list, paired independent loads)
//   into their word accumulator; the 7 replicas of word w+1 publish to LDS.
// Everything double-buffered on iteration parity -> one barrier per iter.
__global__ __launch_bounds__(1024) void nms_kernel(const u64* __restrict__ mask,
                                                   u64* __restrict__ keepw) {
    __shared__ u64 pub[2][8];
    __shared__ int klist[2][64];
    __shared__ int kcnt[2];
    int t = threadIdx.x;
    int lane = t & 63;
    int wid = t >> 6;

    if (t < 2) kcnt[t] = 0;
    if (t < 16) pub[t >> 3][t & 7] = 0;
    __syncthreads();

    if (wid == 0) {
        u64 Sreg = 0;
        u64 diag = mask[(size_t)lane * 128 + 0];       // diag block chunk 0
        u64 colp = mask[(size_t)lane * 128 + 1];       // col 1 of chunk 0
        for (int w = 0; w < 128; ++w) {
            int wn = (w + 1 < 128) ? (w + 1) : 127;
            int wc = (wn + 1 < 128) ? (wn + 1) : 127;
            // issue next-iter prefetches first (a full decide+barrier to land)
            u64 diag_n = mask[(size_t)(64 * wn + lane) * 128 + wn];
            u64 col_n  = mask[(size_t)(64 * wn + lane) * 128 + wc];
            // decide chunk w
            u64 keptm = 0, covered = Sreg;
            int p = 0;
            while (p < 64) {
                u64 cand = ~covered & ((~0ull) << p);
                if (!cand) break;
                int u = (int)__builtin_ctzll(cand);
                keptm |= (1ull << u);
                covered |= readlane64(diag, u);
                p = u + 1;
            }
            int par = w & 1;
            if ((keptm >> lane) & 1ull) {
                int pos = __popcll(keptm & ((1ull << lane) - 1ull));
                klist[par][pos] = lane;
            }
            if (lane == 0) { kcnt[par] = __popcll(keptm); keepw[w] = keptm; }
            __syncthreads();
            // assemble remv word w+1
            u64 sel = ((keptm >> lane) & 1ull) ? colp : 0ull;
            sel = wave_or64(sel);
            u64 P = pub[par][0] | pub[par][1] | pub[par][2] | pub[par][3]
                  | pub[par][4] | pub[par][5] | pub[par][6];
            Sreg = P | sel;
            diag = diag_n; colp = col_n;
        }
    } else if (wid >= 2) {
        int ai = t - 128;
        int myword = ai & 127;
        int slot = ai >> 7;                    // 0..6
        u64 acc = 0;
        for (int w = 0; w < 128; ++w) {
            if (w > 0 && myword > w) {
                int par = (w - 1) & 1;
                int cnt = kcnt[par];
                size_t rowbase = (size_t)(64 * (w - 1)) * 128 + (size_t)myword;
                int i = slot;
                for (; i + 7 < cnt; i += 14) {
                    int r0 = klist[par][i], r1 = klist[par][i + 7];
                    u64 v0 = mask[rowbase + (size_t)r0 * 128];
                    u64 v1 = mask[rowbase + (size_t)r1 * 128];
                    acc |= v0 | v1;
                }
                if (i < cnt) acc |= mask[rowbase + (size_t)klist[par][i] * 128];
            }
            if (myword == w + 1) pub[w & 1][slot] = acc;
            __syncthreads();
        }
    } else {
        for (int w = 0; w < 128; ++w) __syncthreads();
    }
}

// K4: pair fusion + masking, writes fused (8192x7) then keep (8192) to d_out
__global__ __launch_bounds__(256) void fuse_kernel(const float* __restrict__ boxes1,
                                                   const int* __restrict__ order,
                                                   const float* __restrict__ soa,
                                                   const float* __restrict__ sboxes,
                                                   const u64* __restrict__ keepw,
                                                   float* __restrict__ out, int N) {
    int s = blockIdx.x * 256 + threadIdx.x;
    bool keep = (keepw[s >> 6] >> (s & 63)) & 1ull;
    float res[7];
    if (!keep) {
        #pragma unroll
        for (int c = 0; c < 7; ++c) res[c] = 0.0f;
    } else {
        int o = order[s];
        float a[7];
        #pragma unroll
        for (int c = 0; c < 7; ++c) a[c] = sboxes[(size_t)s * 7 + c];
        if (o >= N) {
            #pragma unroll
            for (int c = 0; c < 7; ++c) res[c] = a[c];
        } else {
            float bv[7];
            #pragma unroll
            for (int c = 0; c < 7; ++c) bv[c] = boxes1[(size_t)o * 7 + c];
            DBox da;
            da.x1 = soa[0 * NBOX + s]; da.x2 = soa[1 * NBOX + s];
            da.z1 = soa[2 * NBOX + s]; da.z2 = soa[3 * NBOX + s];
            da.area = soa[4 * NBOX + s]; da.ymin = soa[5 * NBOX + s];
            da.ymax = soa[6 * NBOX + s]; da.h = soa[7 * NBOX + s];
            DBox db = derive_box(bv);
            float iaa = iou_pair(da, da);
            float iab = iou_pair(da, db);
            float ibb = iou_pair(db, db);
            float im0 = fmaxf(iaa, iab);
            float im1 = fmaxf(iab, ibb);
            bool m0 = im0 > THRF, m1 = im1 > THRF;
            float w0 = m0 ? im0 : 0.0f;
            float w1 = m1 ? im1 : 0.0f;
            float den = __fadd_rn(w0, w1);
            float den_safe = (den == 0.0f) ? 1.0f : den;
            bool any = m0 || m1;
            #pragma unroll
            for (int c = 0; c < 7; ++c) {
                float fw = __fdiv_rn(__fadd_rn(__fmul_rn(a[c], w0), __fmul_rn(bv[c], w1)), den_safe);
                float fm = __fmul_rn(__fadd_rn(a[c], bv[c]), 0.5f);
                res[c] = any ? fw : fm;
            }
        }
    }
    #pragma unroll
    for (int c = 0; c < 7; ++c) out[(size_t)s * 7 + c] = res[c];
    out[(size_t)NBOX * 7 + s] = keep ? 1.0f : 0.0f;
}

extern "C" void kernel_launch(void* const* d_in, const int* in_sizes, int n_in,
                              void* d_out, int out_size, void* d_ws, size_t ws_size,
                              hipStream_t stream) {
    (void)n_in; (void)out_size; (void)ws_size;
    const float* boxes0  = (const float*)d_in[0];
    const float* boxes1  = (const float*)d_in[1];
    const float* scores0 = (const float*)d_in[2];
    const float* scores1 = (const float*)d_in[3];
    int N = in_sizes[2];   // 4096

    char* ws = (char*)d_ws;
    int*   order  = (int*)(ws + WS_ORDER);
    float* soa    = (float*)(ws + WS_SOA);
    float* sboxes = (float*)(ws + WS_SBOX);
    u64*   keepw  = (u64*)(ws + WS_KEEPW);
    u64*   mask   = (u64*)(ws + WS_MASK);
    float* out    = (float*)d_out;

    sortprep_kernel<<<NBOX / 64, 64, 0, stream>>>(scores0, scores1, boxes0, boxes1,
                                                  order, soa, sboxes, N);
    mask_kernel<<<256, 256, 0, stream>>>(soa, mask);
    nms_kernel <<<1, 1024, 0, stream>>>(mask, keepw);
    fuse_kernel<<<NBOX / 256, 256, 0, stream>>>(boxes1, order, soa, sboxes, keepw, out, N);
}

// Round 4
// 705.816 us; speedup vs baseline: 3.8011x; 1.2389x over previous
//
#include <hip/hip_runtime.h>
#include <stdint.h>

typedef unsigned long long u64;
typedef uint32_t u32;

#define NBOX 8192
#define THRF 0.3f
#define EPSF 1e-6f

// ---------- ws layout (bytes) ----------
// order   : [65536,   98304)   int[8192]
// soa     : [98304,  360448)   8 arrays of float[8192]
// sboxes  : [360448, 589824)   float[8192*7]
// keepw   : [589824, 590848)   u64[128]
// diag    : [655360, 720896)   u64[128*64] row-major diagonal 64x64 blocks
// bt      : [1048576, 9437184) u64[128*128*64] bit-transposed 64x64 blocks
//           bt[(br*128+bc)*64 + lane]: bit r = suppress(row 64br+r -> col 64bc+lane)

#define WS_ORDER  65536
#define WS_SOA    98304
#define WS_SBOX   360448
#define WS_KEEPW  589824
#define WS_DIAG   655360
#define WS_BT     1048576

struct DBox { float x1, x2, z1, z2, area, ymin, ymax, h; };

__device__ __forceinline__ DBox derive_box(const float v[7]) {
    float cx = v[0], cy = v[1], cz = v[2];
    float dx = __fmul_rn(v[3], 0.5f);
    float dz = __fmul_rn(v[4], 0.5f);
    float h = v[5], yaw = v[6];
    float c = cosf(yaw), sn = sinf(yaw);
    float A = __fmul_rn(dx, c), B = __fmul_rn(dz, sn);
    float P = __fmul_rn(dx, sn), Q = __fmul_rn(dz, c);
    float mX = fmaxf(fabsf(__fadd_rn(A, B)), fabsf(__fsub_rn(A, B)));
    float mZ = fmaxf(fabsf(__fadd_rn(P, Q)), fabsf(__fsub_rn(P, Q)));
    DBox d;
    d.x1 = __fsub_rn(cx, mX); d.x2 = __fadd_rn(cx, mX);
    d.z1 = __fsub_rn(cz, mZ); d.z2 = __fadd_rn(cz, mZ);
    d.area = __fmul_rn(__fsub_rn(d.x2, d.x1), __fsub_rn(d.z2, d.z1));
    float hh = __fmul_rn(h, 0.5f);
    d.ymin = __fsub_rn(cy, hh); d.ymax = __fadd_rn(cy, hh);
    d.h = h;
    return d;
}

__device__ __forceinline__ float iou_pair(const DBox& a, const DBox& b) {
    float yov = fmaxf(__fsub_rn(fminf(a.ymax, b.ymax), fmaxf(a.ymin, b.ymin)), 0.0f);
    float hun = __fsub_rn(__fadd_rn(a.h, b.h), yov);
    float hr  = __fdiv_rn(yov, __fadd_rn(hun, EPSF));
    float xw  = fmaxf(__fsub_rn(fminf(a.x2, b.x2), fmaxf(a.x1, b.x1)), 0.0f);
    float zw  = fmaxf(__fsub_rn(fminf(a.z2, b.z2), fmaxf(a.z1, b.z1)), 0.0f);
    float inter = __fmul_rn(xw, zw);
    float uni = __fsub_rn(__fadd_rn(a.area, b.area), inter);
    return __fmul_rn(__fdiv_rn(inter, __fadd_rn(uni, EPSF)), hr);
}

__device__ __forceinline__ u64 readlane64(u64 v, int lane) {
    u32 lo = (u32)__builtin_amdgcn_readlane((int)(u32)(v & 0xffffffffull), lane);
    u32 hi = (u32)__builtin_amdgcn_readlane((int)(u32)(v >> 32), lane);
    return ((u64)hi << 32) | (u64)lo;
}

__device__ __forceinline__ float readlane_f(float v, int lane) {
    return __uint_as_float((u32)__builtin_amdgcn_readlane((int)__float_as_uint(v), lane));
}

// K1: fused key-build + O(n^2) rank + gather/derive. 128 blocks x 1 wave.
__global__ __launch_bounds__(64) void sortprep_kernel(const float* __restrict__ s0,
                                                      const float* __restrict__ s1,
                                                      const float* __restrict__ boxes0,
                                                      const float* __restrict__ boxes1,
                                                      int* __restrict__ order,
                                                      float* __restrict__ soa,
                                                      float* __restrict__ sboxes, int N) {
    __shared__ u64 lk[NBOX];           // 64 KiB
    int tid = threadIdx.x;
    for (int j = tid; j < NBOX; j += 64) {
        float sc = (j < N) ? s0[j] : s1[j - N];
        lk[j] = ((u64)(~__float_as_uint(sc)) << 13) | (u32)j;   // scores>=0
    }
    __syncthreads();
    int e = blockIdx.x * 64 + tid;
    u64 k = lk[e];
    int rank = 0;
    const ulonglong2* p2 = (const ulonglong2*)lk;
    #pragma unroll 8
    for (int j = 0; j < NBOX / 2; ++j) {
        ulonglong2 v = p2[j];
        rank += (v.x < k);
        rank += (v.y < k);
    }
    order[rank] = e;
    const float* bp = (e < N) ? boxes0 + (size_t)e * 7 : boxes1 + (size_t)(e - N) * 7;
    float v[7];
    #pragma unroll
    for (int c = 0; c < 7; ++c) { v[c] = bp[c]; sboxes[(size_t)rank * 7 + c] = v[c]; }
    DBox d = derive_box(v);
    soa[0 * NBOX + rank] = d.x1;  soa[1 * NBOX + rank] = d.x2;
    soa[2 * NBOX + rank] = d.z1;  soa[3 * NBOX + rank] = d.z2;
    soa[4 * NBOX + rank] = d.area; soa[5 * NBOX + rank] = d.ymin;
    soa[6 * NBOX + rank] = d.ymax; soa[7 * NBOX + rank] = d.h;
}

// K2: bit-transposed suppression blocks. One wave per 64x64 block pair (br<=bc).
// Lane j builds bt word: bit r = (row 64br+r suppresses col 64bc+j).
// For diagonal pairs additionally emits the row-major diag block via ballot.
__global__ __launch_bounds__(64) void maskbt_kernel(const float* __restrict__ soa,
                                                    u64* __restrict__ bt,
                                                    u64* __restrict__ diag) {
    int bc = blockIdx.x, br = blockIdx.y;
    if (bc < br) return;
    int lane = threadIdx.x;
    DBox cb;
    cb.x1   = soa[0 * NBOX + 64 * bc + lane];
    cb.x2   = soa[1 * NBOX + 64 * bc + lane];
    cb.z1   = soa[2 * NBOX + 64 * bc + lane];
    cb.z2   = soa[3 * NBOX + 64 * bc + lane];
    cb.area = soa[4 * NBOX + 64 * bc + lane];
    cb.ymin = soa[5 * NBOX + 64 * bc + lane];
    cb.ymax = soa[6 * NBOX + 64 * bc + lane];
    cb.h    = soa[7 * NBOX + 64 * bc + lane];
    float rv[8];
    #pragma unroll
    for (int a = 0; a < 8; ++a) rv[a] = soa[a * NBOX + 64 * br + lane];
    u64 btw = 0, dw = 0;
    bool isdiag = (br == bc);
    for (int r = 0; r < 64; ++r) {
        DBox rb;
        rb.x1   = readlane_f(rv[0], r);
        rb.x2   = readlane_f(rv[1], r);
        rb.z1   = readlane_f(rv[2], r);
        rb.z2   = readlane_f(rv[3], r);
        rb.area = readlane_f(rv[4], r);
        rb.ymin = readlane_f(rv[5], r);
        rb.ymax = readlane_f(rv[6], r);
        rb.h    = readlane_f(rv[7], r);
        float iou = iou_pair(rb, cb);
        bool pred = (iou >= THRF);
        if (isdiag) pred = pred && (lane > r);
        btw |= pred ? (1ull << r) : 0ull;
        if (isdiag) {
            u64 bal = __ballot(pred);
            if (lane == r) dw = bal;
        }
    }
    bt[((size_t)br * 128 + (size_t)bc) * 64 + lane] = btw;
    if (isdiag) diag[(size_t)br * 64 + lane] = dw;
}

// K3: greedy NMS. 16 waves; wave wid owns remv words v with v%16==wid (8 each,
// in registers). Per iteration w: all waves fold chunk w-1 into their words via
// one ballot per word (bt block (w-1,v) prefetched 2 iters ahead, static addr);
// the wave owning word w runs the serial in-chunk decide and publishes keptm.
// One barrier per iteration; no memory latency on the critical path.
__global__ __launch_bounds__(1024) void nms_kernel(const u64* __restrict__ bt,
                                                   const u64* __restrict__ diag,
                                                   u64* __restrict__ keepw) {
    __shared__ u64 keptm_sh[2];
    int t = threadIdx.x, lane = t & 63, wid = t >> 6;
    u64 acc[8], dreg[8], btp[8], btq[8];
    #pragma unroll
    for (int j = 0; j < 8; ++j) {
        int v = wid + 16 * j;
        acc[j] = 0;
        dreg[j] = diag[(size_t)v * 64 + lane];
        btp[j] = bt[((size_t)(0 * 128 + v)) * 64 + lane];
        btq[j] = bt[((size_t)(1 * 128 + v)) * 64 + lane];
    }
    if (wid == 0) {
        u64 keptm = 0, covered = 0, dw = dreg[0];
        int p = 0;
        while (p < 64) {
            u64 cand = ~covered & ((~0ull) << p);
            if (!cand) break;
            int u = (int)__builtin_ctzll(cand);
            keptm |= 1ull << u;
            covered |= readlane64(dw, u);
            p = u + 1;
        }
        if (lane == 0) { keepw[0] = keptm; keptm_sh[0] = keptm; }
    }
    __syncthreads();
    for (int w = 1; w < 128; ++w) {
        u64 km = keptm_sh[(w - 1) & 1];
        int wnext = (w + 1 < 128) ? (w + 1) : 0;   // clamp: dead but in-bounds
        u64 btn[8];
        #pragma unroll
        for (int j = 0; j < 8; ++j)
            btn[j] = bt[((size_t)(wnext * 128 + (wid + 16 * j))) * 64 + lane];
        #pragma unroll
        for (int j = 0; j < 8; ++j) {
            bool bit = (btp[j] & km) != 0ull;
            acc[j] |= __ballot(bit);
        }
        if ((w & 15) == wid) {
            int jj = w >> 4;
            u64 covered = 0, dw = 0;
            #pragma unroll
            for (int j = 0; j < 8; ++j) if (j == jj) { covered = acc[j]; dw = dreg[j]; }
            u64 keptm = 0;
            int p = 0;
            while (p < 64) {
                u64 cand = ~covered & ((~0ull) << p);
                if (!cand) break;
                int u = (int)__builtin_ctzll(cand);
                keptm |= 1ull << u;
                covered |= readlane64(dw, u);
                p = u + 1;
            }
            if (lane == 0) { keepw[w] = keptm; keptm_sh[w & 1] = keptm; }
        }
        #pragma unroll
        for (int j = 0; j < 8; ++j) { btp[j] = btq[j]; btq[j] = btn[j]; }
        __syncthreads();
    }
}

// K4: pair fusion + masking, writes fused (8192x7) then keep (8192) to d_out
__global__ __launch_bounds__(256) void fuse_kernel(const float* __restrict__ boxes1,
                                                   const int* __restrict__ order,
                                                   const float* __restrict__ soa,
                                                   const float* __restrict__ sboxes,
                                                   const u64* __restrict__ keepw,
                                                   float* __restrict__ out, int N) {
    int s = blockIdx.x * 256 + threadIdx.x;
    bool keep = (keepw[s >> 6] >> (s & 63)) & 1ull;
    float res[7];
    if (!keep) {
        #pragma unroll
        for (int c = 0; c < 7; ++c) res[c] = 0.0f;
    } else {
        int o = order[s];
        float a[7];
        #pragma unroll
        for (int c = 0; c < 7; ++c) a[c] = sboxes[(size_t)s * 7 + c];
        if (o >= N) {
            #pragma unroll
            for (int c = 0; c < 7; ++c) res[c] = a[c];
        } else {
            float bv[7];
            #pragma unroll
            for (int c = 0; c < 7; ++c) bv[c] = boxes1[(size_t)o * 7 + c];
            DBox da;
            da.x1 = soa[0 * NBOX + s]; da.x2 = soa[1 * NBOX + s];
            da.z1 = soa[2 * NBOX + s]; da.z2 = soa[3 * NBOX + s];
            da.area = soa[4 * NBOX + s]; da.ymin = soa[5 * NBOX + s];
            da.ymax = soa[6 * NBOX + s]; da.h = soa[7 * NBOX + s];
            DBox db = derive_box(bv);
            float iaa = iou_pair(da, da);
            float iab = iou_pair(da, db);
            float ibb = iou_pair(db, db);
            float im0 = fmaxf(iaa, iab);
            float im1 = fmaxf(iab, ibb);
            bool m0 = im0 > THRF, m1 = im1 > THRF;
            float w0 = m0 ? im0 : 0.0f;
            float w1 = m1 ? im1 : 0.0f;
            float den = __fadd_rn(w0, w1);
            float den_safe = (den == 0.0f) ? 1.0f : den;
            bool any = m0 || m1;
            #pragma unroll
            for (int c = 0; c < 7; ++c) {
                float fw = __fdiv_rn(__fadd_rn(__fmul_rn(a[c], w0), __fmul_rn(bv[c], w1)), den_safe);
                float fm = __fmul_rn(__fadd_rn(a[c], bv[c]), 0.5f);
                res[c] = any ? fw : fm;
            }
        }
    }
    #pragma unroll
    for (int c = 0; c < 7; ++c) out[(size_t)s * 7 + c] = res[c];
    out[(size_t)NBOX * 7 + s] = keep ? 1.0f : 0.0f;
}

extern "C" void kernel_launch(void* const* d_in, const int* in_sizes, int n_in,
                              void* d_out, int out_size, void* d_ws, size_t ws_size,
                              hipStream_t stream) {
    (void)n_in; (void)out_size; (void)ws_size;
    const float* boxes0  = (const float*)d_in[0];
    const float* boxes1  = (const float*)d_in[1];
    const float* scores0 = (const float*)d_in[2];
    const float* scores1 = (const float*)d_in[3];
    int N = in_sizes[2];   // 4096

    char* ws = (char*)d_ws;
    int*   order  = (int*)(ws + WS_ORDER);
    float* soa    = (float*)(ws + WS_SOA);
    float* sboxes = (float*)(ws + WS_SBOX);
    u64*   keepw  = (u64*)(ws + WS_KEEPW);
    u64*   diag   = (u64*)(ws + WS_DIAG);
    u64*   bt     = (u64*)(ws + WS_BT);
    float* out    = (float*)d_out;

    sortprep_kernel<<<NBOX / 64, 64, 0, stream>>>(scores0, scores1, boxes0, boxes1,
                                                  order, soa, sboxes, N);
    maskbt_kernel<<<dim3(128, 128), 64, 0, stream>>>(soa, bt, diag);
    nms_kernel <<<1, 1024, 0, stream>>>(bt, diag, keepw);
    fuse_kernel<<<NBOX / 256, 256, 0, stream>>>(boxes1, order, soa, sboxes, keepw, out, N);
}